// Round 7
// baseline (196.382 us; speedup 1.0000x reference)
//
#include <hip/hip_runtime.h>
#include <math.h>

// CTC forward loss, linear-domain alpha recursion, power-of-2 renorm.
// B=256 -> one block per batch. Round-15: minimal consumer.
// R13/R14 nulls + pk-issue audit (v_pk_*_f32 = 4cy issue, not 2) showed the
// CONSUMER is the pacer at ~90cy/step. Cuts this round:
//  1. eps pre-added by PRODUCERS (2 pk_add/chunk; slack) -> CMT deleted.
//  2. blank read twice (broadcast, conflict-free) -> CB is a natural pair;
//     banks are 4-reg groups (c1,c3,cb,cb) multiplied in place.
//  3. ALPHA split around the wait: 6 head ops (independent of bank regs)
//     issue BEFORE s_waitcnt lgkmcnt(11); 3 tail muls after; then 4 reissue
//     reads. Uniform lgkmcnt(11) (15-deep lgkm counter; drain proof in
//     notes). Consumer/step ~41cy issue.
// Producers: R14 dual-wave layout (even/odd chunks, per-wave 16-chunk ring,
// vmcnt(15)), plus the eps pk_adds between wait and ds_write.
//   wave0 consumer | wave1 chunks 0,2,.. | wave2 chunks 1,3,..
// Sync: s_barrier per 8-row group, staging G=g+2, 32-row LDS ring. 129
// barriers per wave (deadlock-checked).

#define T_DIM 1024
#define C_DIM 128
#define U_DIM 128
#define LN2F  0.6931471805599453f

#define EPS_LIT "0x33d6bf95"   /* 1e-7f */

// ---- consumer macros ------------------------------------------------------
// head: everything not touching bank regs (16cy)
#define ALPHA_HEAD \
  "v_mov_b32_dpp v118, v115 wave_shr:1 row_mask:0xf bank_mask:0xf bound_ctrl:0\n\t" \
  "v_mov_b32 v119, v114\n\t" \
  "v_pk_add_f32 v[126:127], v[114:115], v[112:113]\n\t" \
  "v_pk_fma_f32 v[126:127], v[118:119], v[30:31], v[126:127]\n\t" \
  "v_pk_add_f32 v[112:113], v[112:113], v[118:119]\n\t" \
  "v_add_f32 v117, v115, v116\n\t"

// tail: multiply by this row's (c1,c3) pair BP, (cb,cb) pair CBP, cb CB0
#define ALPHA_TAIL(BP,CBP,CB0) \
  "v_pk_mul_f32 v[114:115], v[126:127], " BP "\n\t" \
  "v_pk_mul_f32 v[112:113], v[112:113], " CBP "\n\t" \
  "v_mul_f32 v116, v117, " CB0 "\n\t"

#define RENORM \
  "v_max_f32 v127, v112, v113\n\t" \
  "v_max_f32 v127, v127, v114\n\t" \
  "v_max_f32 v127, v127, v115\n\t" \
  "v_max_f32 v127, v127, v116\n\t" \
  "s_nop 1\n\t" \
  "v_max_f32_dpp v127, v127, v127 row_ror:8 row_mask:0xf bank_mask:0xf\n\t" \
  "s_nop 1\n\t" \
  "v_max_f32_dpp v127, v127, v127 row_ror:4 row_mask:0xf bank_mask:0xf\n\t" \
  "s_nop 1\n\t" \
  "v_max_f32_dpp v127, v127, v127 row_ror:2 row_mask:0xf bank_mask:0xf\n\t" \
  "s_nop 1\n\t" \
  "v_max_f32_dpp v127, v127, v127 row_ror:1 row_mask:0xf bank_mask:0xf\n\t" \
  "s_nop 1\n\t" \
  "v_readlane_b32 s91, v127, 0\n\t" \
  "v_readlane_b32 s92, v127, 16\n\t" \
  "v_readlane_b32 s93, v127, 32\n\t" \
  "v_readlane_b32 s94, v127, 48\n\t" \
  "s_nop 1\n\t" \
  "s_max_u32 s91, s91, s92\n\t" \
  "s_max_u32 s93, s93, s94\n\t" \
  "s_max_u32 s91, s91, s93\n\t" \
  "s_lshr_b32 s92, s91, 23\n\t" \
  "s_and_b32 s92, s92, 0xff\n\t" \
  "s_sub_u32 s93, 0x126, s92\n\t" \
  "s_min_u32 s93, s93, 0xfe\n\t" \
  "s_lshl_b32 s94, s93, 23\n\t" \
  "s_sub_u32 s95, 0x7f, s93\n\t" \
  "s_add_u32 %[EA], %[EA], s95\n\t" \
  "v_mul_f32 v112, s94, v112\n\t" \
  "v_mul_f32 v113, s94, v113\n\t" \
  "v_mul_f32 v114, s94, v114\n\t" \
  "v_mul_f32 v115, s94, v115\n\t" \
  "v_mul_f32 v116, s94, v116\n\t"

// step: head | wait bank (issued 4 steps ago) | tail muls | reissue 4 reads
#define ST(...) ST_X(__VA_ARGS__)
#define ST_X(B0,B1,B2,B3,BP,CBP,CB0,ROFF,RBOFF) \
  ALPHA_HEAD \
  "s_waitcnt lgkmcnt(11)\n\t" \
  ALPHA_TAIL(BP,CBP,CB0) \
  "ds_read_b32 " B0 ", v12 offset:" ROFF "\n\t" \
  "ds_read_b32 " B1 ", v13 offset:" ROFF "\n\t" \
  "ds_read_b32 " B2 ", v14 offset:" RBOFF "\n\t" \
  "ds_read_b32 " B3 ", v14 offset:" RBOFF "\n\t"

// bank bundles (k = t & 3): c1, c3, cb, cbdup, (c1:c3), (cb:cb), cb
#define K0 "v96","v97","v98","v99","v[96:97]","v[98:99]","v98"
#define K1 "v100","v101","v102","v103","v[100:101]","v[102:103]","v102"
#define K2 "v104","v105","v106","v107","v[104:105]","v[106:107]","v106"
#define K3 "v108","v109","v110","v111","v[108:109]","v[110:111]","v110"

// ---- producer macros (stride 0x800 = every other 1KB chunk) ---------------
#define PF2(SL) \
  "global_load_dwordx4 v[" SL "], v10, %[P]\n\t" \
  "v_add_u32 v10, 0x800, v10\n\t"
// wait oldest, add eps in place, stage, replenish
#define PWL2(PA,PB,SL,OFF) \
  "s_waitcnt vmcnt(15)\n\t" \
  "v_pk_add_f32 v[" PA "], v[" PA "], v[24:25]\n\t" \
  "v_pk_add_f32 v[" PB "], v[" PB "], v[24:25]\n\t" \
  "ds_write_b128 v11, v[" SL "] offset:" OFF "\n\t" \
  "global_load_dwordx4 v[" SL "], v10, %[P]\n\t" \
  "v_add_u32 v10, 0x800, v10\n\t"
// tail write (no replenish, descending vmcnt)
#define PW2(VC,PA,PB,SL,OFF) \
  "s_waitcnt vmcnt(" VC ")\n\t" \
  "v_pk_add_f32 v[" PA "], v[" PA "], v[24:25]\n\t" \
  "v_pk_add_f32 v[" PB "], v[" PB "], v[24:25]\n\t" \
  "ds_write_b128 v11, v[" SL "] offset:" OFF "\n\t"
#define PBAR \
  "s_waitcnt lgkmcnt(0)\n\t" \
  "s_barrier\n\t"

__global__ __launch_bounds__(192) void ctc_alpha_kernel(
    const int*   __restrict__ y_true,   // (B, U) int32
    const float* __restrict__ y_pred,   // (B, T, C) f32 softmax probs
    float*       __restrict__ out,      // (B, 1) f32
    int B)
{
  __shared__ float4 ldsbuf[1024];       // 16 KB: 32-row x 512 B ring

  const int b = blockIdx.x;
  if (b >= B) return;
  const int tid  = threadIdx.x;
  const int lane = tid & 63;
  const int wid  = tid >> 6;
  const unsigned lds_off = (unsigned)(uintptr_t)(void*)ldsbuf;

  if (wid >= 1) {
    // ---------------- producer waves (A: wid=1 even chunks, B: wid=2 odd) --
    const float* __restrict__ p = y_pred + (size_t)b * (T_DIM * C_DIM);
    const int boff   = (wid == 2) ? 1024 : 0;
    const int gvoff  = lane * 16 + boff;
    const int wraddr = (int)lds_off + lane * 16 + boff;
    asm volatile(
      "s_mov_b32 m0, -1\n\t"
      "v_mov_b32 v10, %[GV]\n\t"
      "v_mov_b32 v11, %[WA]\n\t"
      "v_mov_b32 v24, " EPS_LIT "\n\t"
      "v_mov_b32 v25, " EPS_LIT "\n\t"
      // 16 prologue loads (this wave's chunks 0..15)
      PF2("32:35") PF2("36:39") PF2("40:43") PF2("44:47")
      PF2("48:51") PF2("52:55") PF2("56:59") PF2("60:63")
      PF2("64:67") PF2("68:71") PF2("72:75") PF2("76:79")
      PF2("80:83") PF2("84:87") PF2("88:91") PF2("92:95")
      // pre-P0: stage groups 0,1
      PWL2("32:33","34:35","32:35","0")    PWL2("36:37","38:39","36:39","2048")
      PWL2("40:41","42:43","40:43","4096") PWL2("44:45","46:47","44:47","6144")
      PBAR                                   // P0: rows 0..15 visible
      // main loop: 14 iters x 8 slots (slots 0..111; stage G=slot+2)
      "s_mov_b32 s90, 14\n"
      "LP_%=:\n\t"
      PBAR PWL2("48:49","50:51","48:51","8192")   PWL2("52:53","54:55","52:55","10240")
      PBAR PWL2("56:57","58:59","56:59","12288")  PWL2("60:61","62:63","60:63","14336")
      PBAR PWL2("64:65","66:67","64:67","0")      PWL2("68:69","70:71","68:71","2048")
      PBAR PWL2("72:73","74:75","72:75","4096")   PWL2("76:77","78:79","76:79","6144")
      PBAR PWL2("80:81","82:83","80:83","8192")   PWL2("84:85","86:87","84:87","10240")
      PBAR PWL2("88:89","90:91","88:91","12288")  PWL2("92:93","94:95","92:95","14336")
      PBAR PWL2("32:33","34:35","32:35","0")      PWL2("36:37","38:39","36:39","2048")
      PBAR PWL2("40:41","42:43","40:43","4096")   PWL2("44:45","46:47","44:47","6144")
      "s_sub_u32 s90, s90, 1\n\t"
      "s_cmp_lg_u32 s90, 0\n\t"
      "s_cbranch_scc1 LP_%=\n\t"
      // explicit slots 112..117 (last PWLs)
      PBAR PWL2("48:49","50:51","48:51","8192")   PWL2("52:53","54:55","52:55","10240")
      PBAR PWL2("56:57","58:59","56:59","12288")  PWL2("60:61","62:63","60:63","14336")
      PBAR PWL2("64:65","66:67","64:67","0")      PWL2("68:69","70:71","68:71","2048")
      PBAR PWL2("72:73","74:75","72:75","4096")   PWL2("76:77","78:79","76:79","6144")
      PBAR PWL2("80:81","82:83","80:83","8192")   PWL2("84:85","86:87","84:87","10240")
      PBAR PWL2("88:89","90:91","88:91","12288")  PWL2("92:93","94:95","92:95","14336")
      // PW slots 118..125: write-only, vmcnt descending 15..0
      PBAR PW2("15","32:33","34:35","32:35","0")    PW2("14","36:37","38:39","36:39","2048")
      PBAR PW2("13","40:41","42:43","40:43","4096") PW2("12","44:45","46:47","44:47","6144")
      PBAR PW2("11","48:49","50:51","48:51","8192") PW2("10","52:53","54:55","52:55","10240")
      PBAR PW2("9","56:57","58:59","56:59","12288") PW2("8","60:61","62:63","60:63","14336")
      PBAR PW2("7","64:65","66:67","64:67","0")     PW2("6","68:69","70:71","68:71","2048")
      PBAR PW2("5","72:73","74:75","72:75","4096")  PW2("4","76:77","78:79","76:79","6144")
      PBAR PW2("3","80:81","82:83","80:83","8192")  PW2("2","84:85","86:87","84:87","10240")
      PBAR PW2("1","88:89","90:91","88:91","12288") PW2("0","92:93","94:95","92:95","14336")
      // slots 126,127: bare barriers
      PBAR
      PBAR
      :
      : [P]"s"(p), [GV]"v"(gvoff), [WA]"v"(wraddr)
      : "v10","v11","v24","v25",
        "v32","v33","v34","v35","v36","v37","v38","v39","v40","v41","v42","v43",
        "v44","v45","v46","v47","v48","v49","v50","v51","v52","v53","v54","v55",
        "v56","v57","v58","v59","v60","v61","v62","v63","v64","v65","v66","v67",
        "v68","v69","v70","v71","v72","v73","v74","v75","v76","v77","v78","v79",
        "v80","v81","v82","v83","v84","v85","v86","v87","v88","v89","v90","v91",
        "v92","v93","v94","v95",
        "s90","scc","memory");
    return;
  }

  // ---------------- consumer wave ----------------
  const int* __restrict__ yb = y_true + b * U_DIM;
  const int blank = C_DIM - 1;
  const int ylab0 = yb[2 * lane];
  const int ylab1 = yb[2 * lane + 1];
  int yprev = blank;
  if (lane > 0) yprev = yb[2 * lane - 1];
  const float allow1 = (lane > 0 && ylab0 != blank && ylab0 != yprev) ? 1.0f : 0.0f;
  const float allow3 = (ylab1 != blank && ylab1 != ylab0)             ? 1.0f : 0.0f;

  const int rd1 = (int)lds_off + ylab0 * 4;    // gather addr, label0
  const int rd3 = (int)lds_off + ylab1 * 4;    // gather addr, label1
  const int rdb = (int)lds_off;                // row base (blank at +508)

  const float init0 = (lane == 0) ? 1.0f : 0.0f;
  float a3out, a4out;
  int   e_acc = 0;

  asm volatile(
    "s_mov_b32 m0, -1\n\t"
    "v_mov_b32 v12, %[R1]\n\t"
    "v_mov_b32 v13, %[R3]\n\t"
    "v_mov_b32 v14, %[RB]\n\t"
    "v_mov_b32 v30, %[L1]\n\t"
    "v_mov_b32 v31, %[L3]\n\t"
    "v_mov_b32 v112, %[I0]\n\t"
    "v_mov_b32 v113, 0\n\t"
    "v_mov_b32 v114, 0\n\t"
    "v_mov_b32 v115, 0\n\t"
    "v_mov_b32 v116, 0\n\t"
    "s_barrier\n\t"                          // P0: rows 0..15 staged (eps'd)
    // prime gathers for rows 0..3 into banks K0..K3 (16 reads)
    "ds_read_b32 v96, v12 offset:0\n\t"
    "ds_read_b32 v97, v13 offset:0\n\t"
    "ds_read_b32 v98, v14 offset:508\n\t"
    "ds_read_b32 v99, v14 offset:508\n\t"
    "ds_read_b32 v100, v12 offset:512\n\t"
    "ds_read_b32 v101, v13 offset:512\n\t"
    "ds_read_b32 v102, v14 offset:1020\n\t"
    "ds_read_b32 v103, v14 offset:1020\n\t"
    "ds_read_b32 v104, v12 offset:1024\n\t"
    "ds_read_b32 v105, v13 offset:1024\n\t"
    "ds_read_b32 v106, v14 offset:1532\n\t"
    "ds_read_b32 v107, v14 offset:1532\n\t"
    "ds_read_b32 v108, v12 offset:1536\n\t"
    "ds_read_b32 v109, v13 offset:1536\n\t"
    "ds_read_b32 v110, v14 offset:2044\n\t"
    "ds_read_b32 v111, v14 offset:2044\n\t"
    // main loop: 32 iters x 32 steps; barrier per 8-row group
    "s_mov_b32 s90, 32\n"
    "LM_%=:\n\t"
    "s_barrier\n\t"
    ST(K0,"2048","2556")   ST(K1,"2560","3068")   ST(K2,"3072","3580")   ST(K3,"3584","4092")
    ST(K0,"4096","4604")   ST(K1,"4608","5116")   ST(K2,"5120","5628")   ST(K3,"5632","6140")
    RENORM
    "s_barrier\n\t"
    ST(K0,"6144","6652")   ST(K1,"6656","7164")   ST(K2,"7168","7676")   ST(K3,"7680","8188")
    ST(K0,"8192","8700")   ST(K1,"8704","9212")   ST(K2,"9216","9724")   ST(K3,"9728","10236")
    RENORM
    "s_barrier\n\t"
    ST(K0,"10240","10748") ST(K1,"10752","11260") ST(K2,"11264","11772") ST(K3,"11776","12284")
    ST(K0,"12288","12796") ST(K1,"12800","13308") ST(K2,"13312","13820") ST(K3,"13824","14332")
    RENORM
    "s_barrier\n\t"
    ST(K0,"14336","14844") ST(K1,"14848","15356") ST(K2,"15360","15868") ST(K3,"15872","16380")
    ST(K0,"0","508")       ST(K1,"512","1020")    ST(K2,"1024","1532")   ST(K3,"1536","2044")
    RENORM
    "s_sub_u32 s90, s90, 1\n\t"
    "s_cmp_lg_u32 s90, 0\n\t"
    "s_cbranch_scc1 LM_%=\n\t"
    "s_waitcnt lgkmcnt(0)\n\t"
    "v_mov_b32 %[O3], v115\n\t"
    "v_mov_b32 %[O4], v116\n\t"
    : [O3]"=v"(a3out), [O4]"=v"(a4out), [EA]"+s"(e_acc)
    : [R1]"v"(rd1), [R3]"v"(rd3), [RB]"v"(rdb),
      [L1]"v"(allow1), [L3]"v"(allow3), [I0]"v"(init0)
    : "v12","v13","v14","v30","v31",
      "v96","v97","v98","v99","v100","v101","v102","v103",
      "v104","v105","v106","v107","v108","v109","v110","v111",
      "v112","v113","v114","v115","v116","v117","v118","v119",
      "v126","v127",
      "s90","s91","s92","s93","s94","s95","scc","memory");

  if (lane == 63) {
    float s = a3out + a4out;           // alpha[255] + alpha[256]
    s = fmaxf(s, 1e-37f);
    float ll = logf(s) + (float)e_acc * LN2F;
    out[b] = -ll;
  }
}

extern "C" void kernel_launch(void* const* d_in, const int* in_sizes, int n_in,
                              void* d_out, int out_size, void* d_ws, size_t ws_size,
                              hipStream_t stream) {
  const int*   y_true = (const int*)d_in[0];
  const float* y_pred = (const float*)d_in[1];
  float*       out    = (float*)d_out;
  const int B = in_sizes[0] / U_DIM;   // 256
  ctc_alpha_kernel<<<dim3(B), dim3(192), 0, stream>>>(y_true, y_pred, out, B);
}

// Round 8
// 195.258 us; speedup vs baseline: 1.0058x; 1.0058x over previous
//
#include <hip/hip_runtime.h>
#include <math.h>

// CTC forward loss, linear-domain alpha recursion, power-of-2 renorm.
// Round-16: STATE-SPLIT recursion. The alpha band is lower-triangular in s
// (state s needs only s-1,s-2), so the 257 states split across two waves:
//   wave0 (A): states 0..127   (2/lane)
//   wave1 (B): states 128..256 (2/lane + state 256 on lane 63 slot a4),
//              lagging A by one 8-step group.
//   wave2 (P): producer (R13 single-wave staging + eps pre-add).
// Seam: A writes hist[t-1] = alpha_{t-1}[127] (delayed 1 step, pre-scaled by
// its last renorm inverse so each group's entries sit in the PREVIOUS group
// scale), publishes its pre-renorm exponent eApub[g] per group; B reads
// hist[t-1], scales by f = 2^(eApub[g-1]-eB) (dormant-B: eB snaps to eApub),
// injects into lane0's x via cndmask. All per-state arithmetic is identical
// to R15; renorm is per-wave (exact power-of-2 bookkeeping, e_acc per wave).
// Pipeline: P stages group s in interval s-1; A group g in interval g+1;
// B group g in interval g+2. Ring slots {k+1,k,k-1,k-2} mod 4 disjoint.
// 130 barriers on every wave. A ends groups with lgkmcnt(2) drain (hist
// write is first op of each step); B needs no drain. Uniform waits:
// A lgkm(9), B lgkm(6) - verified by queue enumeration incl. primes.
//
// LDS map (bytes): 0..16383 ring (32 rows x 512B) | 16384 hist (hist[t-1]
// at 16384+t*4) | 20608 hist dump (lanes!=63) | 24704 eApub[g] (g*4) |
// 25216 eA dump.

#define T_DIM 1024
#define C_DIM 128
#define U_DIM 128
#define LN2F  0.6931471805599453f

#define EPS_LIT "0x33d6bf95"   /* 1e-7f */
#define ONE_LIT "0x3f800000"

// ---- wave A step: states 2l (blank), 2l+1 (label y[l]) -------------------
// order puts the hist WRITE first (value = old a1 x sInv), so the group-end
// lgkmcnt(2) drain leaves only the last step's 2 reads in flight.
#define STA(...) STA_X(__VA_ARGS__)
#define STA_X(C1,CB,RIMM,BIMM,HIMM) \
  "v_mul_f32 v44, s80, v51\n\t" \
  "ds_write_b32 v42, v44 offset:" HIMM "\n\t" \
  "v_mov_b32_dpp v52, v51 wave_shr:1 row_mask:0xf bank_mask:0xf bound_ctrl:0\n\t" \
  "v_add_f32 v53, v51, v50\n\t" \
  "v_fma_f32 v53, v52, v45, v53\n\t" \
  "v_add_f32 v50, v50, v52\n\t" \
  "s_waitcnt lgkmcnt(9)\n\t" \
  "v_mul_f32 v51, v53, " C1 "\n\t" \
  "v_mul_f32 v50, v50, " CB "\n\t" \
  "ds_read_b32 " C1 ", v40 offset:" RIMM "\n\t" \
  "ds_read_b32 " CB ", v41 offset:" BIMM "\n\t"

#define KA0 "v96","v97"
#define KA1 "v98","v99"
#define KA2 "v100","v101"
#define KA3 "v102","v103"

// ---- wave B step: states 128+2l, 129+2l (+ s256 as a4 on lane63) ----------
#define STB(...) STB_X(__VA_ARGS__)
#define STB_X(H,C1,CB,RIMM,BIMM,HRIMM) \
  "v_mov_b32_dpp v52, v51 wave_shr:1 row_mask:0xf bank_mask:0xf bound_ctrl:0\n\t" \
  "s_waitcnt lgkmcnt(6)\n\t" \
  "v_mul_f32 v44, s82, " H "\n\t" \
  "v_cndmask_b32 v52, v52, v44, %[M]\n\t" \
  "v_add_f32 v53, v51, v50\n\t" \
  "v_fma_f32 v53, v52, v45, v53\n\t" \
  "v_add_f32 v50, v50, v52\n\t" \
  "v_add_f32 v55, v54, v51\n\t" \
  "v_mul_f32 v51, v53, " C1 "\n\t" \
  "v_mul_f32 v50, v50, " CB "\n\t" \
  "v_mul_f32 v54, v55, " CB "\n\t" \
  "ds_read_b32 " H ", v42 offset:" HRIMM "\n\t" \
  "ds_read_b32 " C1 ", v40 offset:" RIMM "\n\t" \
  "ds_read_b32 " CB ", v41 offset:" BIMM "\n\t"

#define KB0 "v96","v97","v98"
#define KB1 "v99","v100","v101"
#define KB2 "v102","v103","v104"
#define KB3 "v105","v106","v107"

// ---- shared wave-reduce core (v60 -> s91) ---------------------------------
#define REDUCE60 \
  "s_nop 1\n\t" \
  "v_max_f32_dpp v60, v60, v60 row_ror:8 row_mask:0xf bank_mask:0xf\n\t" \
  "s_nop 1\n\t" \
  "v_max_f32_dpp v60, v60, v60 row_ror:4 row_mask:0xf bank_mask:0xf\n\t" \
  "s_nop 1\n\t" \
  "v_max_f32_dpp v60, v60, v60 row_ror:2 row_mask:0xf bank_mask:0xf\n\t" \
  "s_nop 1\n\t" \
  "v_max_f32_dpp v60, v60, v60 row_ror:1 row_mask:0xf bank_mask:0xf\n\t" \
  "s_nop 1\n\t" \
  "v_readlane_b32 s91, v60, 0\n\t" \
  "v_readlane_b32 s92, v60, 16\n\t" \
  "v_readlane_b32 s93, v60, 32\n\t" \
  "v_readlane_b32 s94, v60, 48\n\t" \
  "s_nop 1\n\t" \
  "s_max_u32 s91, s91, s92\n\t" \
  "s_max_u32 s93, s93, s94\n\t" \
  "s_max_u32 s91, s91, s93\n\t"

// A renorm: scale a0,a1; update eA (s81); produce sInv (s80).
#define RENORM_A \
  "v_max_f32 v60, v50, v51\n\t" \
  REDUCE60 \
  "s_lshr_b32 s92, s91, 23\n\t" \
  "s_and_b32 s92, s92, 0xff\n\t" \
  "s_sub_u32 s93, 0x126, s92\n\t" \
  "s_min_u32 s93, s93, 0xfe\n\t" \
  "s_lshl_b32 s94, s93, 23\n\t" \
  "s_sub_u32 s95, 0x7f, s93\n\t" \
  "s_add_u32 s81, s81, s95\n\t" \
  "s_sub_u32 s95, 0xfe, s93\n\t" \
  "s_lshl_b32 s80, s95, 23\n\t" \
  "v_mul_f32 v50, s94, v50\n\t" \
  "v_mul_f32 v51, s94, v51\n\t"

// B renorm: scale a0,a1,a4; zero-max-guarded e update; capture dormancy s84.
#define RENORM_B \
  "v_max3_f32 v60, v50, v51, v54\n\t" \
  REDUCE60 \
  "s_lshr_b32 s92, s91, 23\n\t" \
  "s_and_b32 s92, s92, 0xff\n\t" \
  "s_mov_b32 s84, s92\n\t" \
  "s_sub_u32 s93, 0x126, s92\n\t" \
  "s_min_u32 s93, s93, 0xfe\n\t" \
  "s_lshl_b32 s94, s93, 23\n\t" \
  "s_cmp_lg_u32 s92, 0\n\t" \
  "s_cselect_b32 s95, s93, 0x7f\n\t" \
  "s_sub_u32 s95, 0x7f, s95\n\t" \
  "s_add_u32 s81, s81, s95\n\t" \
  "v_mul_f32 v50, s94, v50\n\t" \
  "v_mul_f32 v51, s94, v51\n\t" \
  "v_mul_f32 v54, s94, v54\n\t"

// B per-group factor for NEXT group: eAprev = readfirstlane(v24).
// dormant (s84==0): eB := eAprev (delta 0). f = 2^clamp(delta+127,[0,254]).
#define FACTOR_B \
  "v_readfirstlane_b32 s83, v24\n\t" \
  "s_nop 1\n\t" \
  "s_cmp_lg_u32 s84, 0\n\t" \
  "s_cselect_b32 s81, s81, s83\n\t" \
  "s_sub_i32 s85, s83, s81\n\t" \
  "s_add_i32 s85, s85, 0x7f\n\t" \
  "s_cmp_lt_i32 s85, 0\n\t" \
  "s_cselect_b32 s85, 0, s85\n\t" \
  "s_cmp_gt_i32 s85, 0xfe\n\t" \
  "s_cselect_b32 s85, 0xfe, s85\n\t" \
  "s_lshl_b32 s82, s85, 23\n\t"

// A group-start publish of pre-renorm exponent.
#define PUBA(GIMM) \
  "v_mov_b32 v44, s81\n\t" \
  "ds_write_b32 v43, v44 offset:" GIMM "\n\t"

#define ENDA \
  "s_waitcnt lgkmcnt(2)\n\t" \
  "s_barrier\n\t"

// ---- producer macros (R13 single-wave + eps pre-add) ----------------------
#define PF(SL) \
  "global_load_dwordx4 v[" SL "], v10, %[P]\n\t" \
  "v_add_u32 v10, 0x400, v10\n\t"
#define PWLE(PA,PB,SL,OFF) \
  "s_waitcnt vmcnt(15)\n\t" \
  "v_pk_add_f32 v[" PA "], v[" PA "], v[24:25]\n\t" \
  "v_pk_add_f32 v[" PB "], v[" PB "], v[24:25]\n\t" \
  "ds_write_b128 v11, v[" SL "] offset:" OFF "\n\t" \
  "global_load_dwordx4 v[" SL "], v10, %[P]\n\t" \
  "v_add_u32 v10, 0x400, v10\n\t"
#define PWE(VC,PA,PB,SL,OFF) \
  "s_waitcnt vmcnt(" VC ")\n\t" \
  "v_pk_add_f32 v[" PA "], v[" PA "], v[24:25]\n\t" \
  "v_pk_add_f32 v[" PB "], v[" PB "], v[24:25]\n\t" \
  "ds_write_b128 v11, v[" SL "] offset:" OFF "\n\t"
#define PBAR \
  "s_waitcnt lgkmcnt(0)\n\t" \
  "s_barrier\n\t"

__global__ __launch_bounds__(192) void ctc_alpha_kernel(
    const int*   __restrict__ y_true,   // (B, U) int32
    const float* __restrict__ y_pred,   // (B, T, C) f32 softmax probs
    float*       __restrict__ out,      // (B, 1) f32
    int B)
{
  __shared__ float4 ldsbuf[2048];       // 32 KB (ring+hist+dumps+eA)

  const int b = blockIdx.x;
  if (b >= B) return;
  const int tid  = threadIdx.x;
  const int lane = tid & 63;
  const int wid  = tid >> 6;
  const unsigned lds_off = (unsigned)(uintptr_t)(void*)ldsbuf;
  const int blank = C_DIM - 1;

  if (wid == 2) {
    // ---------------- producer wave ----------------
    const float* __restrict__ p = y_pred + (size_t)b * (T_DIM * C_DIM);
    const int gvoff  = lane * 16;
    const int wraddr = (int)lds_off + lane * 16;
    asm volatile(
      "s_mov_b32 m0, -1\n\t"
      "v_mov_b32 v10, %[GV]\n\t"
      "v_mov_b32 v11, %[WA]\n\t"
      "v_mov_b32 v24, " EPS_LIT "\n\t"
      "v_mov_b32 v25, " EPS_LIT "\n\t"
      PF("32:35") PF("36:39") PF("40:43") PF("44:47")
      PF("48:51") PF("52:55") PF("56:59") PF("60:63")
      PF("64:67") PF("68:71") PF("72:75") PF("76:79")
      PF("80:83") PF("84:87") PF("88:91") PF("92:95")
      // prestage groups 0,1 (chunks 0..7)
      PWLE("32:33","34:35","32:35","0")    PWLE("36:37","38:39","36:39","1024")
      PWLE("40:41","42:43","40:43","2048") PWLE("44:45","46:47","44:47","3072")
      PWLE("48:49","50:51","48:51","4096") PWLE("52:53","54:55","52:55","5120")
      PWLE("56:57","58:59","56:59","6144") PWLE("60:61","62:63","60:63","7168")
      PBAR                                  // bar1
      // loop: 30 x 4 groups (groups 2..121)
      "s_mov_b32 s90, 30\n"
      "LP_%=:\n\t"
      PWLE("64:65","66:67","64:67","8192")   PWLE("68:69","70:71","68:71","9216")
      PWLE("72:73","74:75","72:75","10240")  PWLE("76:77","78:79","76:79","11264")
      PBAR
      PWLE("80:81","82:83","80:83","12288")  PWLE("84:85","86:87","84:87","13312")
      PWLE("88:89","90:91","88:91","14336")  PWLE("92:93","94:95","92:95","15360")
      PBAR
      PWLE("32:33","34:35","32:35","0")      PWLE("36:37","38:39","36:39","1024")
      PWLE("40:41","42:43","40:43","2048")   PWLE("44:45","46:47","44:47","3072")
      PBAR
      PWLE("48:49","50:51","48:51","4096")   PWLE("52:53","54:55","52:55","5120")
      PWLE("56:57","58:59","56:59","6144")   PWLE("60:61","62:63","60:63","7168")
      PBAR
      "s_sub_u32 s90, s90, 1\n\t"
      "s_cmp_lg_u32 s90, 0\n\t"
      "s_cbranch_scc1 LP_%=\n\t"
      // groups 122,123 (last refilling stagings; loads reach chunk 511)
      PWLE("64:65","66:67","64:67","8192")   PWLE("68:69","70:71","68:71","9216")
      PWLE("72:73","74:75","72:75","10240")  PWLE("76:77","78:79","76:79","11264")
      PBAR
      PWLE("80:81","82:83","80:83","12288")  PWLE("84:85","86:87","84:87","13312")
      PWLE("88:89","90:91","88:91","14336")  PWLE("92:93","94:95","92:95","15360")
      PBAR
      // groups 124..127: write-only, vmcnt 15..0
      PWE("15","32:33","34:35","32:35","0")     PWE("14","36:37","38:39","36:39","1024")
      PWE("13","40:41","42:43","40:43","2048")  PWE("12","44:45","46:47","44:47","3072")
      PBAR
      PWE("11","48:49","50:51","48:51","4096")  PWE("10","52:53","54:55","52:55","5120")
      PWE("9","56:57","58:59","56:59","6144")   PWE("8","60:61","62:63","60:63","7168")
      PBAR
      PWE("7","64:65","66:67","64:67","8192")   PWE("6","68:69","70:71","68:71","9216")
      PWE("5","72:73","74:75","72:75","10240")  PWE("4","76:77","78:79","76:79","11264")
      PBAR
      PWE("3","80:81","82:83","80:83","12288")  PWE("2","84:85","86:87","84:87","13312")
      PWE("1","88:89","90:91","88:91","14336")  PWE("0","92:93","94:95","92:95","15360")
      PBAR
      // trailing bare barriers -> total 130
      PBAR
      PBAR
      PBAR
      :
      : [P]"s"(p), [GV]"v"(gvoff), [WA]"v"(wraddr)
      : "v10","v11","v24","v25",
        "v32","v33","v34","v35","v36","v37","v38","v39","v40","v41","v42","v43",
        "v44","v45","v46","v47","v48","v49","v50","v51","v52","v53","v54","v55",
        "v56","v57","v58","v59","v60","v61","v62","v63","v64","v65","v66","v67",
        "v68","v69","v70","v71","v72","v73","v74","v75","v76","v77","v78","v79",
        "v80","v81","v82","v83","v84","v85","v86","v87","v88","v89","v90","v91",
        "v92","v93","v94","v95",
        "s90","scc","memory");
    return;
  }

  const int* __restrict__ yb = y_true + b * U_DIM;

  if (wid == 0) {
    // ---------------- wave A: states 0..127 ----------------
    const int ylab = yb[lane];                           // label of state 2l+1
    int yprev = blank;
    if (lane > 0) yprev = yb[lane - 1];
    const float allowA = (lane > 0 && ylab != blank && ylab != yprev) ? 1.0f : 0.0f;
    const int rdC1 = (int)lds_off + ylab * 4;
    const int rdCB = (int)lds_off;
    const int hwA  = (int)lds_off + ((lane == 63) ? 16384 : (20608 + lane * 4));
    const int ewA  = (int)lds_off + ((lane == 63) ? 24704 : (25216 + lane * 4));
    const float init0 = (lane == 0) ? 1.0f : 0.0f;

    asm volatile(
      "s_mov_b32 m0, -1\n\t"
      "v_mov_b32 v40, %[RC]\n\t"
      "v_mov_b32 v41, %[RB]\n\t"
      "v_mov_b32 v42, %[HW]\n\t"
      "v_mov_b32 v43, %[EW]\n\t"
      "v_mov_b32 v45, %[L]\n\t"
      "v_mov_b32 v50, %[I0]\n\t"
      "v_mov_b32 v51, 0\n\t"
      "s_mov_b32 s80, " ONE_LIT "\n\t"
      "s_mov_b32 s81, 0\n\t"
      "s_barrier\n\t"                        // bar1
      // prime: banks rows 0..3 (+3 dummies -> uniform lgkm(9) from step 0)
      "ds_read_b32 v96, v40 offset:0\n\t"
      "ds_read_b32 v97, v41 offset:508\n\t"
      "ds_read_b32 v32, v41 offset:0\n\t"
      "ds_read_b32 v32, v41 offset:0\n\t"
      "ds_read_b32 v98, v40 offset:512\n\t"
      "ds_read_b32 v99, v41 offset:1020\n\t"
      "ds_read_b32 v32, v41 offset:0\n\t"
      "ds_read_b32 v100, v40 offset:1024\n\t"
      "ds_read_b32 v101, v41 offset:1532\n\t"
      "ds_read_b32 v102, v40 offset:1536\n\t"
      "ds_read_b32 v103, v41 offset:2044\n\t"
      // main loop: 32 iters x 4 groups
      "s_mov_b32 s90, 32\n"
      "LA_%=:\n\t"
      PUBA("0")
      STA(KA0,"2048","2556","0")   STA(KA1,"2560","3068","4")
      STA(KA2,"3072","3580","8")   STA(KA3,"3584","4092","12")
      STA(KA0,"4096","4604","16")  STA(KA1,"4608","5116","20")
      STA(KA2,"5120","5628","24")  STA(KA3,"5632","6140","28")
      RENORM_A ENDA
      PUBA("4")
      STA(KA0,"6144","6652","32")  STA(KA1,"6656","7164","36")
      STA(KA2,"7168","7676","40")  STA(KA3,"7680","8188","44")
      STA(KA0,"8192","8700","48")  STA(KA1,"8704","9212","52")
      STA(KA2,"9216","9724","56")  STA(KA3,"9728","10236","60")
      RENORM_A ENDA
      PUBA("8")
      STA(KA0,"10240","10748","64") STA(KA1,"10752","11260","68")
      STA(KA2,"11264","11772","72") STA(KA3,"11776","12284","76")
      STA(KA0,"12288","12796","80") STA(KA1,"12800","13308","84")
      STA(KA2,"13312","13820","88") STA(KA3,"13824","14332","92")
      RENORM_A ENDA
      PUBA("12")
      STA(KA0,"14336","14844","96")  STA(KA1,"14848","15356","100")
      STA(KA2,"15360","15868","104") STA(KA3,"15872","16380","108")
      STA(KA0,"0","508","112")       STA(KA1,"512","1020","116")
      STA(KA2,"1024","1532","120")   STA(KA3,"1536","2044","124")
      RENORM_A ENDA
      "v_add_u32 v42, 128, v42\n\t"
      "v_add_u32 v43, 16, v43\n\t"
      "s_sub_u32 s90, s90, 1\n\t"
      "s_cmp_lg_u32 s90, 0\n\t"
      "s_cbranch_scc1 LA_%=\n\t"
      "s_barrier\n\t"                        // trailing -> 130
      "s_waitcnt lgkmcnt(0)\n\t"
      :
      : [RC]"v"(rdC1), [RB]"v"(rdCB), [HW]"v"(hwA), [EW]"v"(ewA),
        [L]"v"(allowA), [I0]"v"(init0)
      : "v32","v40","v41","v42","v43","v44","v45","v50","v51","v52","v53",
        "v60","v96","v97","v98","v99","v100","v101","v102","v103",
        "s80","s81","s90","s91","s92","s93","s94","s95","scc","memory");
    return;
  }

  // ---------------- wave B: states 128..256 ----------------
  const int ylab = yb[64 + lane];                        // label of state 129+2l
  const int yprev = yb[63 + lane];
  const float allowB = (ylab != blank && ylab != yprev) ? 1.0f : 0.0f;
  const int rdC1 = (int)lds_off + ylab * 4;
  const int rdCB = (int)lds_off;
  const int hrB  = (int)lds_off + 16384;
  const int erB  = (int)lds_off + 24704;
  const unsigned long long mask0 = 1ULL;                 // lane 0
  float a1out, a4out;
  int   e_acc = 0;

  asm volatile(
    "s_mov_b32 m0, -1\n\t"
    "v_mov_b32 v40, %[RC]\n\t"
    "v_mov_b32 v41, %[RB]\n\t"
    "v_mov_b32 v42, %[HR]\n\t"
    "v_mov_b32 v43, %[ER]\n\t"
    "v_mov_b32 v45, %[L]\n\t"
    "v_mov_b32 v50, 0\n\t"
    "v_mov_b32 v51, 0\n\t"
    "v_mov_b32 v54, 0\n\t"
    "s_mov_b32 s82, " ONE_LIT "\n\t"       // f = 1 for group 0
    "s_mov_b32 s81, 0\n\t"                 // eB
    "s_barrier\n\t"                        // bar1
    "s_barrier\n\t"                        // bar2 (A's group 0 hist visible)
    // prime: banks rows 0..3 = [c1,cb,hist] x4 with 3 dummies (lgkm(6) ok)
    "ds_read_b32 v97, v40 offset:0\n\t"
    "ds_read_b32 v98, v41 offset:508\n\t"
    "ds_read_b32 v96, v42 offset:0\n\t"
    "ds_read_b32 v32, v41 offset:0\n\t"
    "ds_read_b32 v32, v41 offset:0\n\t"
    "ds_read_b32 v100, v40 offset:512\n\t"
    "ds_read_b32 v101, v41 offset:1020\n\t"
    "ds_read_b32 v99, v42 offset:4\n\t"
    "ds_read_b32 v32, v41 offset:0\n\t"
    "ds_read_b32 v103, v40 offset:1024\n\t"
    "ds_read_b32 v104, v41 offset:1532\n\t"
    "ds_read_b32 v102, v42 offset:8\n\t"
    "ds_read_b32 v106, v40 offset:1536\n\t"
    "ds_read_b32 v107, v41 offset:2044\n\t"
    "ds_read_b32 v105, v42 offset:12\n\t"
    // main loop: 32 iters x 4 groups (group ends with barrier)
    "s_mov_b32 s90, 32\n"
    "LB_%=:\n\t"
    "ds_read_b32 v24, v43 offset:0\n\t"
    STB(KB0,"2048","2556","16")  STB(KB1,"2560","3068","20")
    STB(KB2,"3072","3580","24")  STB(KB3,"3584","4092","28")
    STB(KB0,"4096","4604","32")  STB(KB1,"4608","5116","36")
    STB(KB2,"5120","5628","40")  STB(KB3,"5632","6140","44")
    RENORM_B FACTOR_B
    "s_barrier\n\t"
    "ds_read_b32 v24, v43 offset:4\n\t"
    STB(KB0,"6144","6652","48")  STB(KB1,"6656","7164","52")
    STB(KB2,"7168","7676","56")  STB(KB3,"7680","8188","60")
    STB(KB0,"8192","8700","64")  STB(KB1,"8704","9212","68")
    STB(KB2,"9216","9724","72")  STB(KB3,"9728","10236","76")
    RENORM_B FACTOR_B
    "s_barrier\n\t"
    "ds_read_b32 v24, v43 offset:8\n\t"
    STB(KB0,"10240","10748","80") STB(KB1,"10752","11260","84")
    STB(KB2,"11264","11772","88") STB(KB3,"11776","12284","92")
    STB(KB0,"12288","12796","96") STB(KB1,"12800","13308","100")
    STB(KB2,"13312","13820","104") STB(KB3,"13824","14332","108")
    RENORM_B FACTOR_B
    "s_barrier\n\t"
    "ds_read_b32 v24, v43 offset:12\n\t"
    STB(KB0,"14336","14844","112") STB(KB1,"14848","15356","116")
    STB(KB2,"15360","15868","120") STB(KB3,"15872","16380","124")
    "v_add_u32 v42, 128, v42\n\t"          // hist base advance BEFORE j28
    STB(KB0,"0","508","0")        STB(KB1,"512","1020","4")
    STB(KB2,"1024","1532","8")    STB(KB3,"1536","2044","12")
    RENORM_B FACTOR_B
    "s_barrier\n\t"
    "v_add_u32 v43, 16, v43\n\t"
    "s_sub_u32 s90, s90, 1\n\t"
    "s_cmp_lg_u32 s90, 0\n\t"
    "s_cbranch_scc1 LB_%=\n\t"
    "s_waitcnt lgkmcnt(0)\n\t"
    "v_mov_b32 %[O3], v51\n\t"
    "v_mov_b32 %[O4], v54\n\t"
    "s_mov_b32 %[EA], s81\n\t"
    : [O3]"=v"(a1out), [O4]"=v"(a4out), [EA]"=s"(e_acc)
    : [RC]"v"(rdC1), [RB]"v"(rdCB), [HR]"v"(hrB), [ER]"v"(erB),
      [L]"v"(allowB), [M]"s"(mask0)
    : "v24","v32","v40","v41","v42","v43","v44","v45","v50","v51","v52","v53",
      "v54","v55","v60","v96","v97","v98","v99","v100","v101","v102","v103",
      "v104","v105","v106","v107",
      "s80","s81","s82","s83","s84","s85","s90","s91","s92","s93","s94","s95",
      "scc","memory");

  if (lane == 63) {
    float s = a1out + a4out;             // alpha[255] + alpha[256]
    s = fmaxf(s, 1e-37f);
    float ll = logf(s) + (float)e_acc * LN2F;
    out[b] = -ll;
  }
}

extern "C" void kernel_launch(void* const* d_in, const int* in_sizes, int n_in,
                              void* d_out, int out_size, void* d_ws, size_t ws_size,
                              hipStream_t stream) {
  const int*   y_true = (const int*)d_in[0];
  const float* y_pred = (const float*)d_in[1];
  float*       out    = (float*)d_out;
  const int B = in_sizes[0] / U_DIM;   // 256
  ctc_alpha_kernel<<<dim3(B), dim3(192), 0, stream>>>(y_true, y_pred, out, B);
}